// Round 3
// baseline (32.897 us; speedup 1.0000x reference)
//
#include <hip/hip_runtime.h>
#include <hip/hip_cooperative_groups.h>

namespace cg = cooperative_groups;

// SuperGlue loss: B=16, N=M=2048, scores [B, N+1, M+1] f32.
// loss_tp[b] = sum_i scores[b, i, col(gt0[b,i])],  col(-1) -> M (dustbin col)
// loss_tn[b] = sum_{j: gt1[b,j]==-1} scores[b, N, j]   (dustbin row)
// out = mean_b( (-tp[b] - tn[b]) / (cnt1[b] + M) )
//
// Latency/launch-overhead bound (~4.5 MB of gather lines; R1==R2 showed the
// gather round trip is not the limiter). Single cooperative dispatch removes
// one graph node (~4 us): phase 1 partials -> grid.sync -> block 0 finale.

#define BB 16
#define NN 2048
#define MM 2048
#define CHUNKS 4           // chunks per batch
#define TPB 512            // threads per block == chunk size
#define NBLK (BB * CHUNKS) // 64 blocks, all co-resident on 256 CUs

__global__ __launch_bounds__(TPB) void sg_fused(
    const int* __restrict__ gt0,       // [B, N]
    const int* __restrict__ gt1,       // [B, M]
    const float* __restrict__ scores,  // [B, N+1, M+1]
    double* __restrict__ ws_sum,       // [NBLK]
    int* __restrict__ ws_cnt,          // [NBLK]
    float* __restrict__ out)           // [1]
{
    const int blk = blockIdx.x;            // 0..NBLK-1
    const int b   = blk / CHUNKS;
    const int c   = blk % CHUNKS;
    const int tid = threadIdx.x;           // 0..TPB-1
    const int idx = c * TPB + tid;         // element index in [0, N)
    const long long bofs = (long long)b * (long long)(NN + 1) * (MM + 1);

    // Three loads; tn (dustbin row) is address-independent of g1, so all of
    // {gt0, gt1, tn} issue in parallel; only the tp gather depends on gt0.
    const int   g0 = gt0[b * NN + idx];
    const int   g1 = gt1[b * MM + idx];
    const float tn = scores[bofs + (long long)NN * (MM + 1) + idx];

    const int col = (g0 < 0) ? MM : g0;    // torch -1 wraps to dustbin col M
    double s = (double)scores[bofs + (long long)idx * (MM + 1) + col];
    int cnt = 0;
    if (g1 == -1) { s += (double)tn; cnt = 1; }

    // wave (64-lane) reduction
    #pragma unroll
    for (int off = 32; off > 0; off >>= 1) {
        s   += __shfl_down(s, off, 64);
        cnt += __shfl_down(cnt, off, 64);
    }
    __shared__ double ls[TPB / 64];
    __shared__ int    lc[TPB / 64];
    const int wave = tid >> 6;
    const int lane = tid & 63;
    if (lane == 0) { ls[wave] = s; lc[wave] = cnt; }
    __syncthreads();
    if (wave == 0) {
        s   = (lane < TPB / 64) ? ls[lane] : 0.0;
        cnt = (lane < TPB / 64) ? lc[lane] : 0;
        #pragma unroll
        for (int off = 4; off > 0; off >>= 1) {
            s   += __shfl_down(s, off, 64);
            cnt += __shfl_down(cnt, off, 64);
        }
        if (lane == 0) {
            ws_sum[blk] = s;
            ws_cnt[blk] = cnt;
        }
    }

    cg::this_grid().sync();   // device-scope barrier + memory visibility

    // Finale: block 0, one wave. Partials are [batch][chunk] contiguous.
    if (blk == 0 && tid < NBLK) {
        double ps = ws_sum[tid];           // L2-resident
        int    pc = ws_cnt[tid];
        // segmented reduce over the 4 chunks of each batch
        ps += __shfl_down(ps, 2, 4);  pc += __shfl_down(pc, 2, 4);
        ps += __shfl_down(ps, 1, 4);  pc += __shfl_down(pc, 1, 4);
        double term = ((tid & 3) == 0) ? (-ps) / (double)(pc + MM) : 0.0;
        // sum the 16 terms (lanes 0,4,...,60 hold them; others are 0)
        #pragma unroll
        for (int off = 32; off > 0; off >>= 1)
            term += __shfl_down(term, off, 64);
        if (tid == 0) out[0] = (float)(term / (double)BB);
    }
}

extern "C" void kernel_launch(void* const* d_in, const int* in_sizes, int n_in,
                              void* d_out, int out_size, void* d_ws, size_t ws_size,
                              hipStream_t stream) {
    const int*   gt0    = (const int*)d_in[0];
    const int*   gt1    = (const int*)d_in[1];
    const float* scores = (const float*)d_in[2];

    double* ws_sum = (double*)d_ws;                                   // 64 * 8 B
    int*    ws_cnt = (int*)((char*)d_ws + NBLK * sizeof(double));     // 64 * 4 B
    float*  out    = (float*)d_out;

    void* args[] = { (void*)&gt0, (void*)&gt1, (void*)&scores,
                     (void*)&ws_sum, (void*)&ws_cnt, (void*)&out };
    hipLaunchCooperativeKernel((void*)sg_fused, dim3(NBLK), dim3(TPB),
                               args, 0, stream);
}

// Round 4
// 10.087 us; speedup vs baseline: 3.2612x; 3.2612x over previous
//
#include <hip/hip_runtime.h>

// SuperGlue loss: B=16, N=M=2048, scores [B, N+1, M+1] f32.
// loss_tp[b] = sum_i scores[b, i, col(gt0[b,i])],  col(-1) -> M (dustbin col)
// loss_tn[b] = sum_{j: gt1[b,j]==-1} scores[b, N, j]   (dustbin row)
// out = mean_b( (-tp[b] - tn[b]) / (cnt1[b] + M) )
//
// Launch-overhead bound (~4.5 MB of gather lines; R1==R2 at 11 us, coop
// launch R3 regressed to 33 us). Single REGULAR kernel node: per-block
// partials + release flag; block 0 acquire-spins then computes the finale.
// 64 blocks on 256 CUs are always co-resident -> no deadlock.

#define BB 16
#define NN 2048
#define MM 2048
#define CHUNKS 4           // chunks per batch
#define TPB 512            // threads per block == chunk size
#define NBLK (BB * CHUNKS) // 64 blocks
#define FLAG_MAGIC 0x5A5A0000u  // never equals 0xAA poison pattern

__global__ __launch_bounds__(TPB) void sg_onepass(
    const int* __restrict__ gt0,       // [B, N]
    const int* __restrict__ gt1,       // [B, M]
    const float* __restrict__ scores,  // [B, N+1, M+1]
    double* __restrict__ ws_sum,       // [NBLK]
    int* __restrict__ ws_cnt,          // [NBLK]
    unsigned int* __restrict__ flags,  // [NBLK]
    float* __restrict__ out)           // [1]
{
    const int blk = blockIdx.x;            // 0..NBLK-1
    const int b   = blk / CHUNKS;
    const int c   = blk % CHUNKS;
    const int tid = threadIdx.x;           // 0..TPB-1
    const int idx = c * TPB + tid;         // element index in [0, N)
    const long long bofs = (long long)b * (long long)(NN + 1) * (MM + 1);

    // {gt0, gt1, tn} issue in parallel; only the tp gather depends on gt0.
    const int   g0 = gt0[b * NN + idx];
    const int   g1 = gt1[b * MM + idx];
    const float tn = scores[bofs + (long long)NN * (MM + 1) + idx];

    const int col = (g0 < 0) ? MM : g0;    // torch -1 wraps to dustbin col M
    double s = (double)scores[bofs + (long long)idx * (MM + 1) + col];
    int cnt = 0;
    if (g1 == -1) { s += (double)tn; cnt = 1; }

    // wave (64-lane) reduction — fixed tree, bitwise deterministic
    #pragma unroll
    for (int off = 32; off > 0; off >>= 1) {
        s   += __shfl_down(s, off, 64);
        cnt += __shfl_down(cnt, off, 64);
    }
    __shared__ double ls[TPB / 64];
    __shared__ int    lc[TPB / 64];
    const int wave = tid >> 6;
    const int lane = tid & 63;
    if (lane == 0) { ls[wave] = s; lc[wave] = cnt; }
    __syncthreads();
    if (wave == 0) {
        s   = (lane < TPB / 64) ? ls[lane] : 0.0;
        cnt = (lane < TPB / 64) ? lc[lane] : 0;
        #pragma unroll
        for (int off = 4; off > 0; off >>= 1) {
            s   += __shfl_down(s, off, 64);
            cnt += __shfl_down(cnt, off, 64);
        }
        if (lane == 0) {
            ws_sum[blk] = s;
            ws_cnt[blk] = cnt;
            __threadfence();  // device scope: partial visible before flag
            __hip_atomic_store(&flags[blk], FLAG_MAGIC | (unsigned)blk,
                               __ATOMIC_RELEASE, __HIP_MEMORY_SCOPE_AGENT);
        }
    }

    // Finale: block 0, wave 0. Spin-acquire each block's flag, then fold.
    if (blk == 0 && tid < NBLK) {
        const unsigned want = FLAG_MAGIC | (unsigned)tid;
        while (__hip_atomic_load(&flags[tid], __ATOMIC_ACQUIRE,
                                 __HIP_MEMORY_SCOPE_AGENT) != want) { }
        double ps = ws_sum[tid];           // L2-resident after acquire
        int    pc = ws_cnt[tid];
        // segmented reduce over the 4 chunks of each batch
        ps += __shfl_down(ps, 2, 4);  pc += __shfl_down(pc, 2, 4);
        ps += __shfl_down(ps, 1, 4);  pc += __shfl_down(pc, 1, 4);
        double term = ((tid & 3) == 0) ? (-ps) / (double)(pc + MM) : 0.0;
        // sum the 16 terms (lanes 0,4,...,60 hold them; others are 0)
        #pragma unroll
        for (int off = 32; off > 0; off >>= 1)
            term += __shfl_down(term, off, 64);
        if (tid == 0) out[0] = (float)(term / (double)BB);
    }
}

extern "C" void kernel_launch(void* const* d_in, const int* in_sizes, int n_in,
                              void* d_out, int out_size, void* d_ws, size_t ws_size,
                              hipStream_t stream) {
    const int*   gt0    = (const int*)d_in[0];
    const int*   gt1    = (const int*)d_in[1];
    const float* scores = (const float*)d_in[2];

    double*       ws_sum = (double*)d_ws;                               // 64*8
    int*          ws_cnt = (int*)((char*)d_ws + NBLK * sizeof(double)); // 64*4
    unsigned int* flags  = (unsigned int*)((char*)d_ws + NBLK * (sizeof(double) + sizeof(int)));
    float*        out    = (float*)d_out;

    sg_onepass<<<NBLK, TPB, 0, stream>>>(gt0, gt1, scores,
                                         ws_sum, ws_cnt, flags, out);
}